// Round 12
// baseline (159.118 us; speedup 1.0000x reference)
//
#include <hip/hip_runtime.h>

// Problem constants (match reference)
#define T_TICKS 128
#define NCHAN   1536
#define NCPAIR  10000
#define NCROSS  30000
#define E_EDGES 120000
#define TG      8              // ticks per group
#define NTG     (T_TICKS / TG) // 16 tick groups
#define NBLK_N  ((NCROSS + 255) / 256)  // 118 blocks (k_feat)
#define NODES_B 32             // nodes per k_gat block (256 thr = 32 nodes x 8 ticks)
#define NBLK_G  ((NCROSS + NODES_B - 1) / NODES_B)  // 938 blocks over nodes
#define CAP     24             // bucket capacity (deg ~ Poisson(4); P(>24) ~ 1e-12)
#define EPB     ((E_EDGES + NBLK_N - 1) / NBLK_N)   // 1017 edges per y==0 block

// ---------------- per-(node,tick) scalars s,p materialized + d-coeffs ----
// s = h.a_src, d = h.a_dst, p = h.Wm where h = nodes @ W_gat + b_gat.
// sp layout: [tg][n][8 ticks x (s,p)] = 64 B record = float2[8] (30.7 MB)
// dcoef[n]: (dB,dA1,dB1,dT)(chA,chB,-,-) = 32 B  (0.96 MB)
//   d(n,t) = dB + xA[chA][t]*dA1 + xB[chB][t]*dB1 + t*dT
// Edge scatter into fixed-capacity uint16 buckets fused into y==0 blocks.

__global__ void k_feat(const float* __restrict__ x,
                       const int* __restrict__ c0, const int* __restrict__ c1,
                       const int* __restrict__ c2,
                       const int* __restrict__ g01, const int* __restrict__ g12,
                       const int* __restrict__ g20,
                       const float* __restrict__ r01,
                       const float* __restrict__ r12,
                       const float* __restrict__ r20,
                       const float* __restrict__ Wg,
                       const float* __restrict__ bg,
                       const float* __restrict__ as_,
                       const float* __restrict__ ad_,
                       const float* __restrict__ Wm,
                       const int* __restrict__ e_src,
                       const int* __restrict__ e_dst,
                       int* __restrict__ counts,
                       unsigned short* __restrict__ bucket,
                       float4* __restrict__ sp4, float4* __restrict__ dc4) {
    const int tid = threadIdx.x;
    const int tg = blockIdx.y;
    // fused edge scatter into uint16 buckets
    if (tg == 0) {
        const int lo = blockIdx.x * EPB;
        const int hi = min(lo + EPB, E_EDGES);
        for (int i = lo + tid; i < hi; i += 256) {
            const int s = e_src[i];
            const int d = e_dst[i];
            const int slot = atomicAdd(&counts[d], 1);
            if (slot < CAP) bucket[(size_t)d * CAP + slot] = (unsigned short)s;
        }
    }
    const int n = blockIdx.x * 256 + tid;
    if (n >= NCROSS) return;

    int iA, iB, m;
    float pA, pB;
    const int* cA;
    const int* cB;
    const float* ray;
    if (n < NCPAIR) {
        m = n; cA = c0; cB = c1; pA = 0.f; pB = 1.f; ray = r01;
        iA = g01[2 * m]; iB = g01[2 * m + 1];
    } else if (n < 2 * NCPAIR) {
        m = n - NCPAIR; cA = c1; cB = c2; pA = 1.f; pB = 2.f; ray = r12;
        iA = g12[2 * m]; iB = g12[2 * m + 1];
    } else {
        m = n - 2 * NCPAIR; cA = c2; cB = c0; pA = 2.f; pB = 0.f; ray = r20;
        iA = g20[2 * m]; iB = g20[2 * m + 1];
    }
    const int chA = cA[iA];
    const int chB = cB[iB];
    const float rx = ray[2 * m];
    const float ry = ray[2 * m + 1];

    // tick-static part of nodes @ W_gat + b (excludes sigA, sigB, tick rows)
    float base[4];
#pragma unroll
    for (int c = 0; c < 4; c++) {
        base[c] = bg[c]
                + (float)iA  * Wg[1 * 4 + c] + (float)chA * Wg[2 * 4 + c]
                + pA         * Wg[4 * 4 + c]
                + (float)iB  * Wg[6 * 4 + c] + (float)chB * Wg[7 * 4 + c]
                + pB         * Wg[9 * 4 + c]
                + rx         * Wg[10 * 4 + c] + ry * Wg[11 * 4 + c];
    }
    float sB = 0, dB = 0, pBs = 0;
    float sA1 = 0, dA1 = 0, pA1 = 0;
    float sB1 = 0, dB1 = 0, pB1 = 0;
    float sT = 0, dT = 0, pT = 0;
#pragma unroll
    for (int c = 0; c < 4; c++) {
        const float va = as_[c], vd = ad_[c], vm = Wm[c];
        sB  += base[c] * va;  dB  += base[c] * vd;  pBs += base[c] * vm;
        sA1 += Wg[c] * va;    dA1 += Wg[c] * vd;    pA1 += Wg[c] * vm;
        sB1 += Wg[5*4+c]*va;  dB1 += Wg[5*4+c]*vd;  pB1 += Wg[5*4+c]*vm;
        sT  += Wg[12*4+c]*va; dT  += Wg[12*4+c]*vd; pT  += Wg[12*4+c]*vm;
    }
    if (tg == 0) {
        dc4[(size_t)n * 2]     = make_float4(dB, dA1, dB1, dT);
        dc4[(size_t)n * 2 + 1] = make_float4(__int_as_float(chA),
                                             __int_as_float(chB), 0.f, 0.f);
    }

    const int t0 = tg * TG;
    const float4 xa0 = *(const float4*)(x + chA * T_TICKS + t0);
    const float4 xa1 = *(const float4*)(x + chA * T_TICKS + t0 + 4);
    const float4 xb0 = *(const float4*)(x + chB * T_TICKS + t0);
    const float4 xb1 = *(const float4*)(x + chB * T_TICKS + t0 + 4);
    const float sa[8] = {xa0.x, xa0.y, xa0.z, xa0.w, xa1.x, xa1.y, xa1.z, xa1.w};
    const float sb[8] = {xb0.x, xb0.y, xb0.z, xb0.w, xb1.x, xb1.y, xb1.z, xb1.w};
    float sv[8], pv[8];
#pragma unroll
    for (int k = 0; k < TG; k++) {
        const float tk = (float)(t0 + k);
        sv[k] = sB  + sa[k] * sA1 + sb[k] * sB1 + tk * sT;
        pv[k] = pBs + sa[k] * pA1 + sb[k] * pB1 + tk * pT;
    }
    float4* rec = sp4 + ((size_t)tg * NCROSS + n) * 4;
    rec[0] = make_float4(sv[0], pv[0], sv[1], pv[1]);
    rec[1] = make_float4(sv[2], pv[2], sv[3], pv[3]);
    rec[2] = make_float4(sv[4], pv[4], sv[5], pv[5]);
    rec[3] = make_float4(sv[6], pv[6], sv[7], pv[7]);
}

// ---------------- GAT aggregation + MLP + sigmoid ----------------
// Wave-cooperative 8x8: 8 lanes = one node's 8 ticks (node=tid>>3, tick=tid&7).
// Per edge-visit the subgroup reads the src's 64-B sp record as 8 adjacent
// float2s -> ONE coalesced request (vs 4 scattered per-lane loads before).
// Bucket/dc4 reads are same-address broadcasts. Per-lane softmax state is
// 3 scalars -> ~32 VGPR, 8 waves/SIMD. Wave divergence = max degree over 8
// degree-sorted nodes. LDS result tile -> contiguous 128-B out stores.

__device__ __forceinline__ void upd(float& mx, float& den, float& p,
                                    const float e, const float pj) {
    const float dif = e - mx;
    const float ex = __expf(-fabsf(dif));
    const bool g = dif > 0.f;
    const float scale = g ? ex : 1.f;
    const float w = g ? 1.f : ex;
    mx = g ? e : mx;
    den = fmaf(den, scale, w);
    p = fmaf(p, scale, w * pj);
}

__global__ void k_gat(const float2* __restrict__ sp2,
                      const float4* __restrict__ dc4,
                      const float* __restrict__ x,
                      const int* __restrict__ counts,
                      const unsigned short* __restrict__ bucket,
                      const float* __restrict__ bm,
                      float* __restrict__ out) {
    const int nb = blockIdx.x;
    const int tg = blockIdx.y;
    const int t0 = tg * TG;
    const int bbase = nb * NODES_B;
    const int tid = threadIdx.x;
    const int wsz = min(NODES_B, NCROSS - bbase);
    const int nsub = tid >> 3;      // 0..31: node within block
    const int tk   = tid & 7;       // 0..7:  tick within group

    __shared__ int perm[NODES_B];
    __shared__ int bins[CAP + 1];
    __shared__ int boff[CAP + 1];
    __shared__ float lres[TG * 40]; // [tick][node], stride 40 (bank-spread)

    // block-local descending-degree counting sort over 32 nodes
    if (tid <= CAP) bins[tid] = 0;
    __syncthreads();
    int dg = 0, lp = 0;
    if (tid < wsz) {
        dg = min(counts[bbase + tid], CAP);
        lp = atomicAdd(&bins[dg], 1);
    }
    __syncthreads();
    if (tid == 0) {
        int run = 0;
        for (int d = CAP; d >= 0; d--) { boff[d] = run; run += bins[d]; }
    }
    __syncthreads();
    if (tid < wsz) perm[boff[dg] + lp] = tid;
    __syncthreads();

    if (nsub < wsz) {
        const int nloc = perm[nsub];
        const int n = bbase + nloc;
        const int deg = min(counts[n], CAP);
        const unsigned short* bkt = bucket + (size_t)n * CAP;

        // own-node d(t0+tk): dc4 broadcast + 32-B coalesced x reads/subgroup
        float dd;
        {
            const float4 cd = dc4[(size_t)n * 2];
            const float4 cq = dc4[(size_t)n * 2 + 1];
            const int chA = __float_as_int(cq.x);
            const int chB = __float_as_int(cq.y);
            const float xa = x[chA * T_TICKS + t0 + tk];
            const float xb = x[chB * T_TICKS + t0 + tk];
            dd = fmaf(xa, cd.y, fmaf(xb, cd.z, fmaf((float)(t0 + tk), cd.w, cd.x)));
        }

        float mx = -INFINITY, den = 0.f, pa = 0.f;
        const float2* spb = sp2 + (size_t)tg * NCROSS * 8;

        int j = 0;
        for (; j + 2 <= deg; j += 2) {
            const int s0 = bkt[j];
            const int s1 = bkt[j + 1];
            const float2 f0 = spb[(size_t)s0 * 8 + tk];  // one 64-B req / subgroup
            const float2 f1 = spb[(size_t)s1 * 8 + tk];
            float e0 = f0.x + dd; e0 = fmaxf(e0, 0.2f * e0);
            upd(mx, den, pa, e0, f0.y);
            float e1 = f1.x + dd; e1 = fmaxf(e1, 0.2f * e1);
            upd(mx, den, pa, e1, f1.y);
        }
        if (j < deg) {
            const float2 f0 = spb[(size_t)bkt[j] * 8 + tk];
            float e0 = f0.x + dd; e0 = fmaxf(e0, 0.2f * e0);
            upd(mx, den, pa, e0, f0.y);
        }

        const float logit = pa / (den + 1e-9f) + bm[0];
        lres[tk * 40 + nloc] = 1.f / (1.f + __expf(-logit));
    }
    __syncthreads();
    // coalesced store: 256 threads = 8 tick-rows x 32 nodes
    {
        const int row = tid >> 5;       // 0..7
        const int col = tid & 31;       // 0..31
        if (col < wsz)
            out[(size_t)(t0 + row) * NCROSS + bbase + col] = lres[row * 40 + col];
    }
}

// ---------------- launch ----------------

extern "C" void kernel_launch(void* const* d_in, const int* in_sizes, int n_in,
                              void* d_out, int out_size, void* d_ws, size_t ws_size,
                              hipStream_t stream) {
    const float* x   = (const float*)d_in[0];
    const int* c0  = (const int*)d_in[1];
    const int* c1  = (const int*)d_in[2];
    const int* c2  = (const int*)d_in[3];
    const int* g01 = (const int*)d_in[4];
    const int* g12 = (const int*)d_in[5];
    const int* g20 = (const int*)d_in[6];
    const float* r01 = (const float*)d_in[7];
    const float* r12 = (const float*)d_in[8];
    const float* r20 = (const float*)d_in[9];
    const int* edges = (const int*)d_in[10];          // [2, E]
    const float* Wg  = (const float*)d_in[11];
    const float* as_ = (const float*)d_in[12];
    const float* ad_ = (const float*)d_in[13];
    const float* bg  = (const float*)d_in[14];
    const float* Wm  = (const float*)d_in[15];
    const float* bm  = (const float*)d_in[16];
    float* out = (float*)d_out;

    const int* e_src = edges;
    const int* e_dst = edges + E_EDGES;

    // workspace layout
    char* ws = (char*)d_ws;
    size_t off = 0;
    int* counts            = (int*)(ws + off);            off += NCROSS * sizeof(int);
    off = (off + 63) & ~(size_t)63;
    unsigned short* bucket = (unsigned short*)(ws + off); off += (size_t)NCROSS * CAP * 2; // 1.44 MB
    off = (off + 63) & ~(size_t)63;
    float4* dc4            = (float4*)(ws + off);         off += (size_t)NCROSS * 32;      // 0.96 MB
    off = (off + 255) & ~(size_t)255;
    float4* sp4            = (float4*)(ws + off);         off += (size_t)NTG * NCROSS * 64; // 30.7 MB
    (void)ws_size; (void)n_in; (void)in_sizes; (void)out_size;

    hipMemsetAsync(counts, 0, NCROSS * sizeof(int), stream);

    dim3 gridF(NBLK_N, NTG);
    k_feat<<<gridF, 256, 0, stream>>>(x, c0, c1, c2, g01, g12, g20,
                                      r01, r12, r20, Wg, bg, as_, ad_, Wm,
                                      e_src, e_dst, counts, bucket, sp4, dc4);
    dim3 gridG(NBLK_G, NTG);
    k_gat<<<gridG, 256, 0, stream>>>((const float2*)sp4, dc4, x, counts,
                                     bucket, bm, out);
}

// Round 13
// 153.964 us; speedup vs baseline: 1.0335x; 1.0335x over previous
//
#include <hip/hip_runtime.h>

// Problem constants (match reference)
#define T_TICKS 128
#define NCHAN   1536
#define NCPAIR  10000
#define NCROSS  30000
#define E_EDGES 120000
#define TG      8              // ticks per group
#define NTG     (T_TICKS / TG) // 16 tick groups
#define NBLK_N  ((NCROSS + 255) / 256)  // 118 blocks (k_feat)
#define NODES_B 32             // nodes per k_gat block (256 thr = 32 nodes x 8 ticks)
#define NBLK_G  ((NCROSS + NODES_B - 1) / NODES_B)  // 938 blocks over nodes
#define CAP     24             // bucket capacity (deg ~ Poisson(4); P(>24) ~ 1e-12)
#define EPB     ((E_EDGES + NBLK_N - 1) / NBLK_N)   // 1017 edges per y==0 block

// ---------------- per-(node,tick) scalars s,p materialized + d-coeffs ----
// s = h.a_src, d = h.a_dst, p = h.Wm where h = nodes @ W_gat + b_gat.
// sp layout: [tg][n][8 ticks x (s,p)] = 64 B record = float2[8] (30.7 MB)
// dcoef[n]: (dB,dA1,dB1,dT)(chA,chB,-,-) = 32 B  (0.96 MB)
//   d(n,t) = dB + xA[chA][t]*dA1 + xB[chB][t]*dB1 + t*dT
// Edge scatter into fixed-capacity uint16 buckets fused into y==0 blocks.

__global__ void k_feat(const float* __restrict__ x,
                       const int* __restrict__ c0, const int* __restrict__ c1,
                       const int* __restrict__ c2,
                       const int* __restrict__ g01, const int* __restrict__ g12,
                       const int* __restrict__ g20,
                       const float* __restrict__ r01,
                       const float* __restrict__ r12,
                       const float* __restrict__ r20,
                       const float* __restrict__ Wg,
                       const float* __restrict__ bg,
                       const float* __restrict__ as_,
                       const float* __restrict__ ad_,
                       const float* __restrict__ Wm,
                       const int* __restrict__ e_src,
                       const int* __restrict__ e_dst,
                       int* __restrict__ counts,
                       unsigned short* __restrict__ bucket,
                       float4* __restrict__ sp4, float4* __restrict__ dc4) {
    const int tid = threadIdx.x;
    const int tg = blockIdx.y;
    // fused edge scatter into uint16 buckets
    if (tg == 0) {
        const int lo = blockIdx.x * EPB;
        const int hi = min(lo + EPB, E_EDGES);
        for (int i = lo + tid; i < hi; i += 256) {
            const int s = e_src[i];
            const int d = e_dst[i];
            const int slot = atomicAdd(&counts[d], 1);
            if (slot < CAP) bucket[(size_t)d * CAP + slot] = (unsigned short)s;
        }
    }
    const int n = blockIdx.x * 256 + tid;
    if (n >= NCROSS) return;

    int iA, iB, m;
    float pA, pB;
    const int* cA;
    const int* cB;
    const float* ray;
    if (n < NCPAIR) {
        m = n; cA = c0; cB = c1; pA = 0.f; pB = 1.f; ray = r01;
        iA = g01[2 * m]; iB = g01[2 * m + 1];
    } else if (n < 2 * NCPAIR) {
        m = n - NCPAIR; cA = c1; cB = c2; pA = 1.f; pB = 2.f; ray = r12;
        iA = g12[2 * m]; iB = g12[2 * m + 1];
    } else {
        m = n - 2 * NCPAIR; cA = c2; cB = c0; pA = 2.f; pB = 0.f; ray = r20;
        iA = g20[2 * m]; iB = g20[2 * m + 1];
    }
    const int chA = cA[iA];
    const int chB = cB[iB];
    const float rx = ray[2 * m];
    const float ry = ray[2 * m + 1];

    // tick-static part of nodes @ W_gat + b (excludes sigA, sigB, tick rows)
    float base[4];
#pragma unroll
    for (int c = 0; c < 4; c++) {
        base[c] = bg[c]
                + (float)iA  * Wg[1 * 4 + c] + (float)chA * Wg[2 * 4 + c]
                + pA         * Wg[4 * 4 + c]
                + (float)iB  * Wg[6 * 4 + c] + (float)chB * Wg[7 * 4 + c]
                + pB         * Wg[9 * 4 + c]
                + rx         * Wg[10 * 4 + c] + ry * Wg[11 * 4 + c];
    }
    float sB = 0, dB = 0, pBs = 0;
    float sA1 = 0, dA1 = 0, pA1 = 0;
    float sB1 = 0, dB1 = 0, pB1 = 0;
    float sT = 0, dT = 0, pT = 0;
#pragma unroll
    for (int c = 0; c < 4; c++) {
        const float va = as_[c], vd = ad_[c], vm = Wm[c];
        sB  += base[c] * va;  dB  += base[c] * vd;  pBs += base[c] * vm;
        sA1 += Wg[c] * va;    dA1 += Wg[c] * vd;    pA1 += Wg[c] * vm;
        sB1 += Wg[5*4+c]*va;  dB1 += Wg[5*4+c]*vd;  pB1 += Wg[5*4+c]*vm;
        sT  += Wg[12*4+c]*va; dT  += Wg[12*4+c]*vd; pT  += Wg[12*4+c]*vm;
    }
    if (tg == 0) {
        dc4[(size_t)n * 2]     = make_float4(dB, dA1, dB1, dT);
        dc4[(size_t)n * 2 + 1] = make_float4(__int_as_float(chA),
                                             __int_as_float(chB), 0.f, 0.f);
    }

    const int t0 = tg * TG;
    const float4 xa0 = *(const float4*)(x + chA * T_TICKS + t0);
    const float4 xa1 = *(const float4*)(x + chA * T_TICKS + t0 + 4);
    const float4 xb0 = *(const float4*)(x + chB * T_TICKS + t0);
    const float4 xb1 = *(const float4*)(x + chB * T_TICKS + t0 + 4);
    const float sa[8] = {xa0.x, xa0.y, xa0.z, xa0.w, xa1.x, xa1.y, xa1.z, xa1.w};
    const float sb[8] = {xb0.x, xb0.y, xb0.z, xb0.w, xb1.x, xb1.y, xb1.z, xb1.w};
    float sv[8], pv[8];
#pragma unroll
    for (int k = 0; k < TG; k++) {
        const float tk = (float)(t0 + k);
        sv[k] = sB  + sa[k] * sA1 + sb[k] * sB1 + tk * sT;
        pv[k] = pBs + sa[k] * pA1 + sb[k] * pB1 + tk * pT;
    }
    float4* rec = sp4 + ((size_t)tg * NCROSS + n) * 4;
    rec[0] = make_float4(sv[0], pv[0], sv[1], pv[1]);
    rec[1] = make_float4(sv[2], pv[2], sv[3], pv[3]);
    rec[2] = make_float4(sv[4], pv[4], sv[5], pv[5]);
    rec[3] = make_float4(sv[6], pv[6], sv[7], pv[7]);
}

// ---------------- GAT aggregation + MLP + sigmoid ----------------
// Wave-cooperative 8x8 (8 lanes = one node's 8 ticks) + XCD-pinned tg slabs:
// 1-D grid, xcd = lid&7, tg = xcd + 8*(s/NBLK_G) -> each tg's 1.92 MB sp
// slab stays in ONE XCD's L2 (R10-proven heuristic). Per edge-visit the
// subgroup reads the src's 64-B sp record as 8 adjacent float2s -> one
// coalesced L2-hit request. 4-edge unroll: one ushort4 bucket broadcast +
// 4 independent gathers in flight. LDS degree sort -> uniform trips;
// LDS result tile -> contiguous out stores.

__device__ __forceinline__ void upd(float& mx, float& den, float& p,
                                    const float e, const float pj) {
    const float dif = e - mx;
    const float ex = __expf(-fabsf(dif));
    const bool g = dif > 0.f;
    const float scale = g ? ex : 1.f;
    const float w = g ? 1.f : ex;
    mx = g ? e : mx;
    den = fmaf(den, scale, w);
    p = fmaf(p, scale, w * pj);
}

__global__ void k_gat(const float2* __restrict__ sp2,
                      const float4* __restrict__ dc4,
                      const float* __restrict__ x,
                      const int* __restrict__ counts,
                      const unsigned short* __restrict__ bucket,
                      const float* __restrict__ bm,
                      float* __restrict__ out) {
    // XCD swizzle: consecutive lids round-robin XCDs; pin tg to XCD tg%8.
    const int lid = blockIdx.x;
    const int xcd = lid & 7;
    const int s   = lid >> 3;            // 0 .. 2*NBLK_G-1
    const int q   = s / NBLK_G;          // 0 or 1
    const int nb  = s - q * NBLK_G;
    const int tg  = xcd + 8 * q;
    const int t0  = tg * TG;
    const int bbase = nb * NODES_B;
    const int tid = threadIdx.x;
    const int wsz = min(NODES_B, NCROSS - bbase);
    const int nsub = tid >> 3;      // 0..31: node within block
    const int tk   = tid & 7;       // 0..7:  tick within group

    __shared__ int perm[NODES_B];
    __shared__ int bins[CAP + 1];
    __shared__ int boff[CAP + 1];
    __shared__ float lres[TG * 40]; // [tick][node], stride 40 (bank-spread)

    // block-local descending-degree counting sort over 32 nodes
    if (tid <= CAP) bins[tid] = 0;
    __syncthreads();
    int dg = 0, lp = 0;
    if (tid < wsz) {
        dg = min(counts[bbase + tid], CAP);
        lp = atomicAdd(&bins[dg], 1);
    }
    __syncthreads();
    if (tid == 0) {
        int run = 0;
        for (int d = CAP; d >= 0; d--) { boff[d] = run; run += bins[d]; }
    }
    __syncthreads();
    if (tid < wsz) perm[boff[dg] + lp] = tid;
    __syncthreads();

    if (nsub < wsz) {
        const int nloc = perm[nsub];
        const int n = bbase + nloc;
        const int deg = min(counts[n], CAP);
        const unsigned short* bkt = bucket + (size_t)n * CAP;

        // own-node d(t0+tk): dc4 broadcast + 32-B coalesced x reads/subgroup
        float dd;
        {
            const float4 cd = dc4[(size_t)n * 2];
            const float4 cq = dc4[(size_t)n * 2 + 1];
            const int chA = __float_as_int(cq.x);
            const int chB = __float_as_int(cq.y);
            const float xa = x[chA * T_TICKS + t0 + tk];
            const float xb = x[chB * T_TICKS + t0 + tk];
            dd = fmaf(xa, cd.y, fmaf(xb, cd.z, fmaf((float)(t0 + tk), cd.w, cd.x)));
        }

        float mx = -INFINITY, den = 0.f, pa = 0.f;
        const float2* spb = sp2 + (size_t)tg * NCROSS * 8;

        int j = 0;
        for (; j + 4 <= deg; j += 4) {
            const ushort4 ss = *(const ushort4*)(bkt + j);  // 8-B broadcast
            const float2 f0 = spb[(size_t)ss.x * 8 + tk];   // 4 indep gathers
            const float2 f1 = spb[(size_t)ss.y * 8 + tk];
            const float2 f2 = spb[(size_t)ss.z * 8 + tk];
            const float2 f3 = spb[(size_t)ss.w * 8 + tk];
            float e;
            e = f0.x + dd; e = fmaxf(e, 0.2f * e); upd(mx, den, pa, e, f0.y);
            e = f1.x + dd; e = fmaxf(e, 0.2f * e); upd(mx, den, pa, e, f1.y);
            e = f2.x + dd; e = fmaxf(e, 0.2f * e); upd(mx, den, pa, e, f2.y);
            e = f3.x + dd; e = fmaxf(e, 0.2f * e); upd(mx, den, pa, e, f3.y);
        }
        for (; j < deg; j++) {
            const float2 f0 = spb[(size_t)bkt[j] * 8 + tk];
            float e0 = f0.x + dd; e0 = fmaxf(e0, 0.2f * e0);
            upd(mx, den, pa, e0, f0.y);
        }

        const float logit = pa / (den + 1e-9f) + bm[0];
        lres[tk * 40 + nloc] = 1.f / (1.f + __expf(-logit));
    }
    __syncthreads();
    // coalesced store: 256 threads = 8 tick-rows x 32 nodes
    {
        const int row = tid >> 5;       // 0..7
        const int col = tid & 31;       // 0..31
        if (col < wsz)
            out[(size_t)(t0 + row) * NCROSS + bbase + col] = lres[row * 40 + col];
    }
}

// ---------------- launch ----------------

extern "C" void kernel_launch(void* const* d_in, const int* in_sizes, int n_in,
                              void* d_out, int out_size, void* d_ws, size_t ws_size,
                              hipStream_t stream) {
    const float* x   = (const float*)d_in[0];
    const int* c0  = (const int*)d_in[1];
    const int* c1  = (const int*)d_in[2];
    const int* c2  = (const int*)d_in[3];
    const int* g01 = (const int*)d_in[4];
    const int* g12 = (const int*)d_in[5];
    const int* g20 = (const int*)d_in[6];
    const float* r01 = (const float*)d_in[7];
    const float* r12 = (const float*)d_in[8];
    const float* r20 = (const float*)d_in[9];
    const int* edges = (const int*)d_in[10];          // [2, E]
    const float* Wg  = (const float*)d_in[11];
    const float* as_ = (const float*)d_in[12];
    const float* ad_ = (const float*)d_in[13];
    const float* bg  = (const float*)d_in[14];
    const float* Wm  = (const float*)d_in[15];
    const float* bm  = (const float*)d_in[16];
    float* out = (float*)d_out;

    const int* e_src = edges;
    const int* e_dst = edges + E_EDGES;

    // workspace layout
    char* ws = (char*)d_ws;
    size_t off = 0;
    int* counts            = (int*)(ws + off);            off += NCROSS * sizeof(int);
    off = (off + 63) & ~(size_t)63;
    unsigned short* bucket = (unsigned short*)(ws + off); off += (size_t)NCROSS * CAP * 2; // 1.44 MB
    off = (off + 63) & ~(size_t)63;
    float4* dc4            = (float4*)(ws + off);         off += (size_t)NCROSS * 32;      // 0.96 MB
    off = (off + 255) & ~(size_t)255;
    float4* sp4            = (float4*)(ws + off);         off += (size_t)NTG * NCROSS * 64; // 30.7 MB
    (void)ws_size; (void)n_in; (void)in_sizes; (void)out_size;

    hipMemsetAsync(counts, 0, NCROSS * sizeof(int), stream);

    dim3 gridF(NBLK_N, NTG);
    k_feat<<<gridF, 256, 0, stream>>>(x, c0, c1, c2, g01, g12, g20,
                                      r01, r12, r20, Wg, bg, as_, ad_, Wm,
                                      e_src, e_dst, counts, bucket, sp4, dc4);
    k_gat<<<NBLK_G * NTG, 256, 0, stream>>>((const float2*)sp4, dc4, x, counts,
                                            bucket, bm, out);
}